// Round 1
// baseline (5581.895 us; speedup 1.0000x reference)
//
#include <hip/hip_runtime.h>
#include <hip/hip_bf16.h>

#define EDIM 256
#define HDIM 512
#define BB 32
#define SS 512
#define CC 2
#define G3 1536   // 3*HDIM

typedef unsigned int u32;

__device__ __forceinline__ float toF(float v) { return v; }
__device__ __forceinline__ float toF(__hip_bfloat16 v) { return __bfloat162float(v); }
__device__ __forceinline__ void storeX(float* p, float v) { *p = v; }
__device__ __forceinline__ void storeX(__hip_bfloat16* p, float v) { *p = __float2bfloat16(v); }

// ---------------- K1: init (zero h double-buffer + barrier counters, compute induced vec) ------------
__global__ void k_init(const float* __restrict__ induction, const float* __restrict__ unk_vec,
                       float* __restrict__ induced, float* __restrict__ h2, u32* __restrict__ ctr) {
  const int t = threadIdx.x;  // 256 threads
  for (int i = t; i < 2 * BB * HDIM; i += 256) h2[i] = 0.f;
  if (t < 32) ctr[t] = 0u;
  float acc = 0.f;
  const float* row = induction + t * EDIM;
#pragma unroll 4
  for (int j = 0; j < EDIM; j += 4) {
    float4 a = *(const float4*)(row + j);
    float4 u = *(const float4*)(unk_vec + j);
    acc += a.x * u.x + a.y * u.y + a.z * u.z + a.w * u.w;
  }
  induced[t] = acc;
}

// ---------------- K2: xi = gather(e) @ W_ih^T + b_ih,   [16384 x 1536] ------------------------------
// 128x128 tile per wg, K-chunks of 32, LDS transposed [k][row] so compute reads are float4.
template <typename XT>
__global__ __launch_bounds__(256) void k_xi(const int* __restrict__ x, const float* __restrict__ emb,
                                            const float* __restrict__ induced,
                                            const float* __restrict__ W_ih, const float* __restrict__ b_ih,
                                            XT* __restrict__ xi) {
  __shared__ float As[32][132];
  __shared__ float Bs[32][132];
  __shared__ int toks[128];
  const int r0 = blockIdx.y * 128;
  const int c0 = blockIdx.x * 128;
  const int tid = threadIdx.x;
  if (tid < 128) toks[tid] = x[r0 + tid];
  __syncthreads();
  const int tr = tid >> 4;      // 0..15
  const int tc = tid & 15;      // 0..15
  const int lr = tid & 127;     // loader row/col
  const int lk = (tid >> 7) * 16;

  float acc[8][8];
#pragma unroll
  for (int i = 0; i < 8; i++)
#pragma unroll
    for (int j = 0; j < 8; j++) acc[i][j] = 0.f;

  for (int kk = 0; kk < EDIM; kk += 32) {
    const int tok = toks[lr];
    const float* asrc = (tok < 0) ? (induced + kk + lk) : (emb + (size_t)tok * EDIM + kk + lk);
    const float* bsrc = W_ih + (size_t)(c0 + lr) * EDIM + kk + lk;
#pragma unroll
    for (int q = 0; q < 4; q++) {
      float4 v = *(const float4*)(asrc + q * 4);
      As[lk + q * 4 + 0][lr] = v.x; As[lk + q * 4 + 1][lr] = v.y;
      As[lk + q * 4 + 2][lr] = v.z; As[lk + q * 4 + 3][lr] = v.w;
      float4 w = *(const float4*)(bsrc + q * 4);
      Bs[lk + q * 4 + 0][lr] = w.x; Bs[lk + q * 4 + 1][lr] = w.y;
      Bs[lk + q * 4 + 2][lr] = w.z; Bs[lk + q * 4 + 3][lr] = w.w;
    }
    __syncthreads();
#pragma unroll
    for (int k = 0; k < 32; k++) {
      float4 a0 = *(const float4*)&As[k][tr * 4];
      float4 a1 = *(const float4*)&As[k][tr * 4 + 64];
      float4 b0 = *(const float4*)&Bs[k][tc * 4];
      float4 b1 = *(const float4*)&Bs[k][tc * 4 + 64];
      float av[8] = {a0.x, a0.y, a0.z, a0.w, a1.x, a1.y, a1.z, a1.w};
      float bv[8] = {b0.x, b0.y, b0.z, b0.w, b1.x, b1.y, b1.z, b1.w};
#pragma unroll
      for (int ri = 0; ri < 8; ri++)
#pragma unroll
        for (int ci = 0; ci < 8; ci++) acc[ri][ci] += av[ri] * bv[ci];
    }
    __syncthreads();
  }
#pragma unroll
  for (int ri = 0; ri < 8; ri++) {
    const int row = r0 + tr * 4 + (ri & 3) + ((ri >> 2) << 6);
#pragma unroll
    for (int ci = 0; ci < 8; ci++) {
      const int col = c0 + tc * 4 + (ci & 3) + ((ci >> 2) << 6);
      storeX(xi + (size_t)row * G3 + col, acc[ri][ci] + b_ih[col]);
    }
  }
}

// ---------------- K3: persistent GRU recurrence -----------------------------------------------------
// 8 groups (4 batch chains each) x 32 wgs. wg m owns hidden units i0=m*16 .. +15 for its 4 chains.
// W_hh slice lives in registers for all 512 steps. Group-local barrier, double-buffered h.
template <typename XT>
__global__ __launch_bounds__(256, 1) void k_gru(const XT* __restrict__ xi, const float* __restrict__ W_hh,
                                                const float* __restrict__ b_hh, float* __restrict__ h2,
                                                float* __restrict__ pooled, u32* __restrict__ ctr) {
  const int wg = blockIdx.x;
  const int g = wg & 7;        // group -> batch quad (XCD-friendly swizzle)
  const int m = wg >> 3;       // member 0..31
  const int bbase = g * 4;
  const int i0 = m * 16;
  const int tid = threadIdx.x;
  const int i2 = tid >> 5;     // 0..7 : pair of hidden units
  const int ks = tid & 31;     // 0..31: k-slice

  // weights: rows (q*H + i) for i = i0+i2*2+{0,1}, k = ks*2 + j*64  (96 fp32 in VGPRs)
  float2 w[2][3][8];
#pragma unroll
  for (int ii = 0; ii < 2; ii++) {
    const int i = i0 + i2 * 2 + ii;
#pragma unroll
    for (int q = 0; q < 3; q++) {
      const float* wrow = W_hh + (size_t)(q * HDIM + i) * HDIM;
#pragma unroll
      for (int j = 0; j < 8; j++) w[ii][q][j] = *(const float2*)(wrow + ks * 2 + j * 64);
    }
  }

  // gate-thread (tid<64) fixed mapping: b4g = tid>>4, ilg = tid&15
  const int ilg = tid & 15;
  const int b4g = tid >> 4;
  float bh0 = b_hh[0 * HDIM + i0 + ilg];
  float bh1 = b_hh[1 * HDIM + i0 + ilg];
  float bh2 = b_hh[2 * HDIM + i0 + ilg];

  __shared__ float hs[4][512];
  __shared__ float red[32][201];

  float pmax = -3.0e38f;

  for (int s = 0; s < SS; s++) {
    const float* hread = h2 + (size_t)(s & 1) * (BB * HDIM);
    float* hwrite = h2 + (size_t)((s + 1) & 1) * (BB * HDIM);

    // early xi loads for this step (no barrier dependency; latency hidden under partials)
    float xr = 0.f, xz = 0.f, xn = 0.f;
    if (tid < 64) {
      const size_t xoff = ((size_t)(bbase + b4g) * SS + s) * G3 + (i0 + ilg);
      xr = toF(xi[xoff]);
      xz = toF(xi[xoff + HDIM]);
      xn = toF(xi[xoff + 2 * HDIM]);
    }

    // stage the group's 4 h rows into LDS (coalesced float4)
#pragma unroll
    for (int u = 0; u < 2; u++) {
      const int f = tid + u * 256;          // 0..511 float4s
      const int b4 = f >> 7;
      const int c4 = (f & 127) << 2;
      *(float4*)&hs[b4][c4] = *(const float4*)(hread + (size_t)(bbase + b4) * HDIM + c4);
    }
    __syncthreads();

    // partial dot products: each thread: 2 units x 3 gates over its 16 k's, for 4 chains
#pragma unroll
    for (int b4 = 0; b4 < 4; b4++) {
      float a00 = 0.f, a01 = 0.f, a02 = 0.f, a10 = 0.f, a11 = 0.f, a12 = 0.f;
#pragma unroll
      for (int j = 0; j < 8; j++) {
        const float2 hv = *(const float2*)&hs[b4][ks * 2 + j * 64];
        a00 += w[0][0][j].x * hv.x + w[0][0][j].y * hv.y;
        a01 += w[0][1][j].x * hv.x + w[0][1][j].y * hv.y;
        a02 += w[0][2][j].x * hv.x + w[0][2][j].y * hv.y;
        a10 += w[1][0][j].x * hv.x + w[1][0][j].y * hv.y;
        a11 += w[1][1][j].x * hv.x + w[1][1][j].y * hv.y;
        a12 += w[1][2][j].x * hv.x + w[1][2][j].y * hv.y;
      }
      const int c0 = (i2 * 2) * 12 + b4 * 3;
      red[ks][c0 + 0] = a00; red[ks][c0 + 1] = a01; red[ks][c0 + 2] = a02;
      red[ks][c0 + 12] = a10; red[ks][c0 + 13] = a11; red[ks][c0 + 14] = a12;
    }
    __syncthreads();

    if (tid < 64) {
      float hr = bh0, hz = bh1, hn = bh2;
      const int c0 = ilg * 12 + b4g * 3;
#pragma unroll 8
      for (int k2 = 0; k2 < 32; k2++) {
        hr += red[k2][c0 + 0];
        hz += red[k2][c0 + 1];
        hn += red[k2][c0 + 2];
      }
      const float r = 1.f / (1.f + expf(-(xr + hr)));
      const float z = 1.f / (1.f + expf(-(xz + hz)));
      const float n = tanhf(xn + r * hn);
      const float hp = hs[b4g][i0 + ilg];
      const float hnew = (1.f - z) * n + z * hp;
      pmax = fmaxf(pmax, hnew);
      hwrite[(size_t)(bbase + b4g) * HDIM + i0 + ilg] = hnew;
    }

    // group barrier: release own h_new, wait for the other 31 wgs, acquire their writes
    __syncthreads();
    if (tid == 0) {
      __builtin_amdgcn_fence(__ATOMIC_RELEASE, "agent");
      __hip_atomic_fetch_add(&ctr[g], 1u, __ATOMIC_RELAXED, __HIP_MEMORY_SCOPE_AGENT);
      const u32 target = (u32)(32 * (s + 1));
      while (__hip_atomic_load(&ctr[g], __ATOMIC_RELAXED, __HIP_MEMORY_SCOPE_AGENT) < target) {
        __builtin_amdgcn_s_sleep(1);
      }
      __builtin_amdgcn_fence(__ATOMIC_ACQUIRE, "agent");
    }
    __syncthreads();
  }

  if (tid < 64) pooled[(size_t)(bbase + b4g) * HDIM + i0 + ilg] = pmax;
}

// ---------------- K4: out = pooled @ W_proj^T + b_proj ----------------------------------------------
__global__ void k_out(const float* __restrict__ pooled, const float* __restrict__ W_proj,
                      const float* __restrict__ b_proj, float* __restrict__ out) {
  const int t = threadIdx.x;  // 64 threads
  const int b = t >> 1, c = t & 1;
  const float* p = pooled + (size_t)b * HDIM;
  const float* wr = W_proj + (size_t)c * HDIM;
  float acc = 0.f;
#pragma unroll 4
  for (int k = 0; k < HDIM; k += 4) {
    float4 pv = *(const float4*)(p + k);
    float4 wv = *(const float4*)(wr + k);
    acc += pv.x * wv.x + pv.y * wv.y + pv.z * wv.z + pv.w * wv.w;
  }
  out[b * CC + c] = acc + b_proj[c];
}

extern "C" void kernel_launch(void* const* d_in, const int* in_sizes, int n_in,
                              void* d_out, int out_size, void* d_ws, size_t ws_size,
                              hipStream_t stream) {
  const int* x = (const int*)d_in[0];
  const float* emb = (const float*)d_in[1];
  const float* unk = (const float*)d_in[2];
  const float* induction = (const float*)d_in[3];
  const float* W_ih = (const float*)d_in[4];
  const float* W_hh = (const float*)d_in[5];
  const float* b_ih = (const float*)d_in[6];
  const float* b_hh = (const float*)d_in[7];
  const float* W_proj = (const float*)d_in[8];
  const float* b_proj = (const float*)d_in[9];
  float* out = (float*)d_out;

  const size_t xi_f32 = (size_t)BB * SS * G3 * 4;
  const size_t xi_b16 = (size_t)BB * SS * G3 * 2;
  const size_t tail = (size_t)2 * BB * HDIM * 4 + (size_t)BB * HDIM * 4 + EDIM * 4 + 128 + 1024;
  const bool usef32 = ws_size >= xi_f32 + tail;

  char* p = (char*)d_ws;
  void* xi = p;
  p += ((usef32 ? xi_f32 : xi_b16) + 255) & ~(size_t)255;
  float* h2 = (float*)p;      p += (size_t)2 * BB * HDIM * 4;
  float* pooled = (float*)p;  p += (size_t)BB * HDIM * 4;
  float* induced = (float*)p; p += EDIM * 4;
  u32* ctr = (u32*)p;

  k_init<<<1, 256, 0, stream>>>(induction, unk, induced, h2, ctr);
  if (usef32) {
    k_xi<float><<<dim3(12, 128), 256, 0, stream>>>(x, emb, induced, W_ih, b_ih, (float*)xi);
    k_gru<float><<<256, 256, 0, stream>>>((const float*)xi, W_hh, b_hh, h2, pooled, ctr);
  } else {
    k_xi<__hip_bfloat16><<<dim3(12, 128), 256, 0, stream>>>(x, emb, induced, W_ih, b_ih,
                                                            (__hip_bfloat16*)xi);
    k_gru<__hip_bfloat16><<<256, 256, 0, stream>>>((const __hip_bfloat16*)xi, W_hh, b_hh, h2, pooled,
                                                   ctr);
  }
  k_out<<<1, 64, 0, stream>>>(pooled, W_proj, b_proj, out);
}

// Round 2
// 2374.537 us; speedup vs baseline: 2.3507x; 2.3507x over previous
//
#include <hip/hip_runtime.h>
#include <hip/hip_bf16.h>

#define EDIM 256
#define HDIM 512
#define BB 32
#define SS 512
#define CC 2
#define G3 1536   // 3*HDIM

typedef unsigned int u32;
typedef unsigned long long u64;

__device__ __forceinline__ float toF(float v) { return v; }
__device__ __forceinline__ float toF(__hip_bfloat16 v) { return __bfloat162float(v); }
__device__ __forceinline__ void storeX(float* p, float v) { *p = v; }
__device__ __forceinline__ void storeX(__hip_bfloat16* p, float v) { *p = __float2bfloat16(v); }

// ---------------- K1: zero tagged h buffer (wgs 0..15) + compute induced vec (wg 16) ---------------
__global__ void k_init(const float* __restrict__ induction, const float* __restrict__ unk_vec,
                       float* __restrict__ induced, u64* __restrict__ thw) {
  const int t = threadIdx.x;  // 256 threads
  const int wg = blockIdx.x;  // 17 wgs
  if (wg < 16) {
    u64* p = thw + (size_t)wg * 2048;  // 16 * 2048 = 32768 u64 = 8 groups * 2 * 2048
    for (int i = t; i < 2048; i += 256) p[i] = 0ull;
  } else {
    float acc = 0.f;
    const float* row = induction + t * EDIM;
#pragma unroll 4
    for (int j = 0; j < EDIM; j += 4) {
      float4 a = *(const float4*)(row + j);
      float4 u = *(const float4*)(unk_vec + j);
      acc += a.x * u.x + a.y * u.y + a.z * u.z + a.w * u.w;
    }
    induced[t] = acc;
  }
}

// ---------------- K2: xi = gather(e) @ W_ih^T + b_ih,   [16384 x 1536] ------------------------------
template <typename XT>
__global__ __launch_bounds__(256) void k_xi(const int* __restrict__ x, const float* __restrict__ emb,
                                            const float* __restrict__ induced,
                                            const float* __restrict__ W_ih, const float* __restrict__ b_ih,
                                            XT* __restrict__ xi) {
  __shared__ float As[32][132];
  __shared__ float Bs[32][132];
  __shared__ int toks[128];
  const int r0 = blockIdx.y * 128;
  const int c0 = blockIdx.x * 128;
  const int tid = threadIdx.x;
  if (tid < 128) toks[tid] = x[r0 + tid];
  __syncthreads();
  const int tr = tid >> 4;
  const int tc = tid & 15;
  const int lr = tid & 127;
  const int lk = (tid >> 7) * 16;

  float acc[8][8];
#pragma unroll
  for (int i = 0; i < 8; i++)
#pragma unroll
    for (int j = 0; j < 8; j++) acc[i][j] = 0.f;

  for (int kk = 0; kk < EDIM; kk += 32) {
    const int tok = toks[lr];
    const float* asrc = (tok < 0) ? (induced + kk + lk) : (emb + (size_t)tok * EDIM + kk + lk);
    const float* bsrc = W_ih + (size_t)(c0 + lr) * EDIM + kk + lk;
#pragma unroll
    for (int q = 0; q < 4; q++) {
      float4 v = *(const float4*)(asrc + q * 4);
      As[lk + q * 4 + 0][lr] = v.x; As[lk + q * 4 + 1][lr] = v.y;
      As[lk + q * 4 + 2][lr] = v.z; As[lk + q * 4 + 3][lr] = v.w;
      float4 w = *(const float4*)(bsrc + q * 4);
      Bs[lk + q * 4 + 0][lr] = w.x; Bs[lk + q * 4 + 1][lr] = w.y;
      Bs[lk + q * 4 + 2][lr] = w.z; Bs[lk + q * 4 + 3][lr] = w.w;
    }
    __syncthreads();
#pragma unroll
    for (int k = 0; k < 32; k++) {
      float4 a0 = *(const float4*)&As[k][tr * 4];
      float4 a1 = *(const float4*)&As[k][tr * 4 + 64];
      float4 b0 = *(const float4*)&Bs[k][tc * 4];
      float4 b1 = *(const float4*)&Bs[k][tc * 4 + 64];
      float av[8] = {a0.x, a0.y, a0.z, a0.w, a1.x, a1.y, a1.z, a1.w};
      float bv[8] = {b0.x, b0.y, b0.z, b0.w, b1.x, b1.y, b1.z, b1.w};
#pragma unroll
      for (int ri = 0; ri < 8; ri++)
#pragma unroll
        for (int ci = 0; ci < 8; ci++) acc[ri][ci] += av[ri] * bv[ci];
    }
    __syncthreads();
  }
#pragma unroll
  for (int ri = 0; ri < 8; ri++) {
    const int row = r0 + tr * 4 + (ri & 3) + ((ri >> 2) << 6);
#pragma unroll
    for (int ci = 0; ci < 8; ci++) {
      const int col = c0 + tc * 4 + (ci & 3) + ((ci >> 2) << 6);
      storeX(xi + (size_t)row * G3 + col, acc[ri][ci] + b_ih[col]);
    }
  }
}

// ---------------- K3: persistent GRU, fence-free tagged-word exchange -------------------------------
// 8 groups (4 chains each) x 32 wgs. wg m owns h units [m*16, m*16+16) for its group's 4 chains.
// h^{s+1}[b4][u] is published as one u64 = (tag=s+1)<<32 | f32bits at slot[parity][b4*512+u].
// Readers poll their 8 words; tag match == data valid. No fences, no counters.
template <typename XT>
__global__ __launch_bounds__(256, 1) void k_gru(const XT* __restrict__ xi, const float* __restrict__ W_hh,
                                                const float* __restrict__ b_hh, u64* __restrict__ thw,
                                                float* __restrict__ pooled) {
  const int wg = blockIdx.x;
  const int g = wg & 7;        // group; wg&7 keeps members XCD-colocated under %8 round-robin (perf only)
  const int m = wg >> 3;
  const int bbase = g * 4;
  const int i0 = m * 16;
  const int tid = threadIdx.x;
  const int i2 = tid >> 5;     // 0..7
  const int ks = tid & 31;     // 0..31

  // W_hh slice in registers: 96 fp32/thread (whole 3MB matrix across the group)
  float2 w[2][3][8];
#pragma unroll
  for (int ii = 0; ii < 2; ii++) {
    const int i = i0 + i2 * 2 + ii;
#pragma unroll
    for (int q = 0; q < 3; q++) {
      const float* wrow = W_hh + (size_t)(q * HDIM + i) * HDIM;
#pragma unroll
      for (int j = 0; j < 8; j++) w[ii][q][j] = *(const float2*)(wrow + ks * 2 + j * 64);
    }
  }

  const int ilg = tid & 15;
  const int b4g = tid >> 4;    // meaningful for tid<64
  const float bh0 = b_hh[0 * HDIM + i0 + ilg];
  const float bh1 = b_hh[1 * HDIM + i0 + ilg];
  const float bh2 = b_hh[2 * HDIM + i0 + ilg];

  u64* slot = thw + (size_t)g * 2 * 2048;

  __shared__ float hs[4][512];       // h^s for the 4 chains
  __shared__ float red[192][34];     // partials: [output o][k-slice], stride 34 -> 2-way max
  __shared__ float gsum[208];

  float* hflat = &hs[0][0];
  float pmax = -3.0e38f;

  for (int s = 0; s < SS; s++) {
    // xi prefetch (independent; latency hides under poll/partials)
    float xr = 0.f, xz = 0.f, xn = 0.f;
    if (tid < 64) {
      const size_t xoff = ((size_t)(bbase + b4g) * SS + s) * G3 + (i0 + ilg);
      xr = toF(xi[xoff]);
      xz = toF(xi[xoff + HDIM]);
      xn = toF(xi[xoff + 2 * HDIM]);
    }

    // acquire h^s
    if (s == 0) {
#pragma unroll
      for (int j = 0; j < 8; j++) hflat[j * 256 + tid] = 0.f;
    } else {
      const u64* src = slot + (size_t)(s & 1) * 2048 + tid;
      const u32 need = (u32)s;
      u64 v[8];
#pragma unroll
      for (int j = 0; j < 8; j++)
        v[j] = __hip_atomic_load(src + j * 256, __ATOMIC_RELAXED, __HIP_MEMORY_SCOPE_AGENT);
      u32 pend = 0;
#pragma unroll
      for (int j = 0; j < 8; j++)
        if ((u32)(v[j] >> 32) != need) pend |= 1u << j;
      int guard = 0;
      while (pend && guard < (1 << 20)) {
        __builtin_amdgcn_s_sleep(2);
#pragma unroll
        for (int j = 0; j < 8; j++)
          if (pend & (1u << j))
            v[j] = __hip_atomic_load(src + j * 256, __ATOMIC_RELAXED, __HIP_MEMORY_SCOPE_AGENT);
#pragma unroll
        for (int j = 0; j < 8; j++)
          if ((pend & (1u << j)) && (u32)(v[j] >> 32) == need) pend &= ~(1u << j);
        guard++;
      }
#pragma unroll
      for (int j = 0; j < 8; j++) hflat[j * 256 + tid] = __uint_as_float((u32)v[j]);
    }
    __syncthreads();

    // partial dots: thread (i2,ks): 2 units x 3 gates x 4 chains over its 16 k's
#pragma unroll
    for (int b4 = 0; b4 < 4; b4++) {
      float a00 = 0.f, a01 = 0.f, a02 = 0.f, a10 = 0.f, a11 = 0.f, a12 = 0.f;
#pragma unroll
      for (int j = 0; j < 8; j++) {
        const float2 hv = *(const float2*)&hs[b4][ks * 2 + j * 64];
        a00 += w[0][0][j].x * hv.x + w[0][0][j].y * hv.y;
        a01 += w[0][1][j].x * hv.x + w[0][1][j].y * hv.y;
        a02 += w[0][2][j].x * hv.x + w[0][2][j].y * hv.y;
        a10 += w[1][0][j].x * hv.x + w[1][0][j].y * hv.y;
        a11 += w[1][1][j].x * hv.x + w[1][1][j].y * hv.y;
        a12 += w[1][2][j].x * hv.x + w[1][2][j].y * hv.y;
      }
      const int o0 = (i2 * 2) * 12 + b4 * 3;
      red[o0 + 0][ks] = a00; red[o0 + 1][ks] = a01; red[o0 + 2][ks] = a02;
      red[o0 + 12][ks] = a10; red[o0 + 13][ks] = a11; red[o0 + 14][ks] = a12;
    }
    __syncthreads();

    // stage A: 192 threads, one output each, float2 row reads
    if (tid < 192) {
      float acc = 0.f;
      const float* r = &red[tid][0];
#pragma unroll
      for (int k = 0; k < 32; k += 2) {
        const float2 t2 = *(const float2*)(r + k);
        acc += t2.x + t2.y;
      }
      gsum[tid] = acc;
    }
    __syncthreads();

    // stage B: 64 gate threads -> h_new, publish tagged word
    if (tid < 64) {
      const int c0 = ilg * 12 + b4g * 3;
      const float hr = bh0 + gsum[c0 + 0];
      const float hz = bh1 + gsum[c0 + 1];
      const float hn = bh2 + gsum[c0 + 2];
      const float r = 1.f / (1.f + expf(-(xr + hr)));
      const float z = 1.f / (1.f + expf(-(xz + hz)));
      const float n = tanhf(xn + r * hn);
      const float hp = hs[b4g][i0 + ilg];
      const float hnew = (1.f - z) * n + z * hp;
      pmax = fmaxf(pmax, hnew);
      const u64 pkt = ((u64)(u32)(s + 1) << 32) | (u64)__float_as_uint(hnew);
      __hip_atomic_store(slot + (size_t)((s + 1) & 1) * 2048 + (b4g * 512 + i0 + ilg), pkt,
                         __ATOMIC_RELAXED, __HIP_MEMORY_SCOPE_AGENT);
    }
    __syncthreads();  // protect hs until stage B consumed it
  }

  if (tid < 64) pooled[(size_t)(bbase + b4g) * HDIM + i0 + ilg] = pmax;
}

// ---------------- K4: out = pooled @ W_proj^T + b_proj ----------------------------------------------
__global__ void k_out(const float* __restrict__ pooled, const float* __restrict__ W_proj,
                      const float* __restrict__ b_proj, float* __restrict__ out) {
  const int t = threadIdx.x;  // 64 threads
  const int b = t >> 1, c = t & 1;
  const float* p = pooled + (size_t)b * HDIM;
  const float* wr = W_proj + (size_t)c * HDIM;
  float acc = 0.f;
#pragma unroll 4
  for (int k = 0; k < HDIM; k += 4) {
    float4 pv = *(const float4*)(p + k);
    float4 wv = *(const float4*)(wr + k);
    acc += pv.x * wv.x + pv.y * wv.y + pv.z * wv.z + pv.w * wv.w;
  }
  out[b * CC + c] = acc + b_proj[c];
}

extern "C" void kernel_launch(void* const* d_in, const int* in_sizes, int n_in,
                              void* d_out, int out_size, void* d_ws, size_t ws_size,
                              hipStream_t stream) {
  const int* x = (const int*)d_in[0];
  const float* emb = (const float*)d_in[1];
  const float* unk = (const float*)d_in[2];
  const float* induction = (const float*)d_in[3];
  const float* W_ih = (const float*)d_in[4];
  const float* W_hh = (const float*)d_in[5];
  const float* b_ih = (const float*)d_in[6];
  const float* b_hh = (const float*)d_in[7];
  const float* W_proj = (const float*)d_in[8];
  const float* b_proj = (const float*)d_in[9];
  float* out = (float*)d_out;

  const size_t xi_f32 = (size_t)BB * SS * G3 * 4;
  const size_t xi_b16 = (size_t)BB * SS * G3 * 2;
  const size_t thw_sz = (size_t)8 * 2 * 2048 * 8;  // 256 KB
  const size_t tail = thw_sz + (size_t)BB * HDIM * 4 + EDIM * 4 + 4096;
  const bool usef32 = ws_size >= xi_f32 + tail;

  char* p = (char*)d_ws;
  void* xi = p;
  p += ((usef32 ? xi_f32 : xi_b16) + 255) & ~(size_t)255;
  u64* thw = (u64*)p;         p += thw_sz;
  float* pooled = (float*)p;  p += (size_t)BB * HDIM * 4;
  float* induced = (float*)p;

  k_init<<<17, 256, 0, stream>>>(induction, unk, induced, thw);
  if (usef32) {
    k_xi<float><<<dim3(12, 128), 256, 0, stream>>>(x, emb, induced, W_ih, b_ih, (float*)xi);
    k_gru<float><<<256, 256, 0, stream>>>((const float*)xi, W_hh, b_hh, thw, pooled);
  } else {
    k_xi<__hip_bfloat16><<<dim3(12, 128), 256, 0, stream>>>(x, emb, induced, W_ih, b_ih,
                                                            (__hip_bfloat16*)xi);
    k_gru<__hip_bfloat16><<<256, 256, 0, stream>>>((const __hip_bfloat16*)xi, W_hh, b_hh, thw, pooled);
  }
  k_out<<<1, 64, 0, stream>>>(pooled, W_proj, b_proj, out);
}

// Round 5
// 2222.130 us; speedup vs baseline: 2.5120x; 1.0686x over previous
//
#include <hip/hip_runtime.h>
#include <hip/hip_bf16.h>

#define EDIM 256
#define HDIM 512
#define BB 32
#define SS 512
#define CC 2
#define G3 1536   // 3*HDIM

typedef unsigned int u32;
typedef unsigned long long u64;
typedef __attribute__((ext_vector_type(8))) short short8;
typedef __attribute__((ext_vector_type(4))) float f32x4;

__device__ __forceinline__ float toF(float v) { return v; }
__device__ __forceinline__ float toF(__hip_bfloat16 v) { return __bfloat162float(v); }
__device__ __forceinline__ void storeX(float* p, float v) { *p = v; }
__device__ __forceinline__ void storeX(__hip_bfloat16* p, float v) { *p = __float2bfloat16(v); }

// fp32 -> bf16 bits, round-to-nearest-even (no dependence on __hip_bfloat16 internals)
__device__ __forceinline__ unsigned short f2bf(float f) {
  u32 b = __float_as_uint(f);
  return (unsigned short)((b + 0x7FFFu + ((b >> 16) & 1u)) >> 16);
}

// ---------------- K1: zero tagged h words (wgs 0..15) + induced vec (wg 16) ------------------------
__global__ void k_init(const float* __restrict__ induction, const float* __restrict__ unk_vec,
                       float* __restrict__ induced, u64* __restrict__ thw) {
  const int t = threadIdx.x;
  const int wg = blockIdx.x;
  if (wg < 16) {
    u64* p = thw + (size_t)wg * 1024;  // 16*1024 = 8 groups * 2 * 1024
    for (int i = t; i < 1024; i += 256) p[i] = 0ull;
  } else {
    float acc = 0.f;
    const float* row = induction + t * EDIM;
#pragma unroll 4
    for (int j = 0; j < EDIM; j += 4) {
      float4 a = *(const float4*)(row + j);
      float4 u = *(const float4*)(unk_vec + j);
      acc += a.x * u.x + a.y * u.y + a.z * u.z + a.w * u.w;
    }
    induced[t] = acc;
  }
}

// ---------------- K2: xi = gather(e) @ W_ih^T + b_ih via bf16 MFMA ----------------------------------
// 128x128 tile, K-chunks of 32. A/B staged fp32->bf16 in LDS. mfma_f32_16x16x32_bf16.
// A-frag: A[m=lane&15][k=(lane>>4)*8+j]; B-frag same (B^T pattern); C/D: row=(lane>>4)*4+reg,
// col=lane&15 (m89-verified mapping).
template <typename XT>
__global__ __launch_bounds__(256) void k_xi(const int* __restrict__ x, const float* __restrict__ emb,
                                            const float* __restrict__ induced,
                                            const float* __restrict__ W_ih, const float* __restrict__ b_ih,
                                            XT* __restrict__ xi) {
  __shared__ __align__(16) unsigned short As[128][40];  // 32 k + 8 pad (80B rows, 16B-aligned)
  __shared__ __align__(16) unsigned short Bs[128][40];
  __shared__ int toks[128];
  __shared__ float bcol[128];
  const int c0 = blockIdx.x * 128;
  const int r0 = blockIdx.y * 128;
  const int tid = threadIdx.x;
  if (tid < 128) { toks[tid] = x[r0 + tid]; bcol[tid] = b_ih[c0 + tid]; }
  __syncthreads();

  const int wv = tid >> 6, ln = tid & 63;
  const int lr = tid & 127, kh = tid >> 7;   // staging: row, k-half (16 k's each)
  const int fm = ln & 15, fq = ln >> 4;      // fragment lane decomposition

  f32x4 acc[2][8];
#pragma unroll
  for (int i = 0; i < 2; i++)
#pragma unroll
    for (int j = 0; j < 8; j++) acc[i][j] = (f32x4){0.f, 0.f, 0.f, 0.f};

  const int tok = toks[lr];
  const float* abase = (tok < 0 ? induced : emb + (size_t)tok * EDIM) + kh * 16;
  const float* bbase = W_ih + (size_t)(c0 + lr) * EDIM + kh * 16;

  for (int kk = 0; kk < EDIM; kk += 32) {
    unsigned short av[16], bv[16];
#pragma unroll
    for (int q = 0; q < 4; q++) {
      float4 ta = *(const float4*)(abase + kk + q * 4);
      float4 tb = *(const float4*)(bbase + kk + q * 4);
      av[q * 4 + 0] = f2bf(ta.x); av[q * 4 + 1] = f2bf(ta.y);
      av[q * 4 + 2] = f2bf(ta.z); av[q * 4 + 3] = f2bf(ta.w);
      bv[q * 4 + 0] = f2bf(tb.x); bv[q * 4 + 1] = f2bf(tb.y);
      bv[q * 4 + 2] = f2bf(tb.z); bv[q * 4 + 3] = f2bf(tb.w);
    }
    // 16 shorts = 32 bytes = TWO uint4 stores (R4 bug: only one was stored)
    *(uint4*)&As[lr][kh * 16 + 0] = *(uint4*)&av[0];
    *(uint4*)&As[lr][kh * 16 + 8] = *(uint4*)&av[8];
    *(uint4*)&Bs[lr][kh * 16 + 0] = *(uint4*)&bv[0];
    *(uint4*)&Bs[lr][kh * 16 + 8] = *(uint4*)&bv[8];
    __syncthreads();

    short8 af0 = *(const short8*)&As[wv * 32 + fm][fq * 8];
    short8 af1 = *(const short8*)&As[wv * 32 + 16 + fm][fq * 8];
#pragma unroll
    for (int ni = 0; ni < 8; ni++) {
      short8 bf = *(const short8*)&Bs[ni * 16 + fm][fq * 8];
      acc[0][ni] = __builtin_amdgcn_mfma_f32_16x16x32_bf16(af0, bf, acc[0][ni], 0, 0, 0);
      acc[1][ni] = __builtin_amdgcn_mfma_f32_16x16x32_bf16(af1, bf, acc[1][ni], 0, 0, 0);
    }
    __syncthreads();
  }

#pragma unroll
  for (int mi = 0; mi < 2; mi++)
#pragma unroll
    for (int ni = 0; ni < 8; ni++) {
      const int col = c0 + ni * 16 + fm;
      const float bb = bcol[ni * 16 + fm];
#pragma unroll
      for (int r = 0; r < 4; r++) {
        const int row = r0 + wv * 32 + mi * 16 + fq * 4 + r;
        storeX(xi + (size_t)row * G3 + col, acc[mi][ni][r] + bb);
      }
    }
}

// ---------------- K3: persistent GRU, packed fence-free tagged exchange ----------------------------
// 8 groups x 32 wgs. Word W = c*256+p holds units (2p,2p+1) of chain c: 24-bit mantissa fp32 pair +
// 16-bit step tag, one relaxed agent-scope u64. Tag match == valid (single-word atomicity), no fences.
template <typename XT>
__global__ __launch_bounds__(256, 1) void k_gru(const XT* __restrict__ xi, const float* __restrict__ W_hh,
                                                const float* __restrict__ b_hh, u64* __restrict__ thw,
                                                float* __restrict__ pooled) {
  const int wg = blockIdx.x;
  const int g = wg & 7;
  const int m = wg >> 3;
  const int bbase = g * 4;
  const int i0 = m * 16;
  const int tid = threadIdx.x;
  const int i2 = tid >> 5;
  const int ks = tid & 31;

  float2 w[2][3][8];  // 96 fp32 W_hh slice
#pragma unroll
  for (int ii = 0; ii < 2; ii++) {
    const int i = i0 + i2 * 2 + ii;
#pragma unroll
    for (int q = 0; q < 3; q++) {
      const float* wrow = W_hh + (size_t)(q * HDIM + i) * HDIM;
#pragma unroll
      for (int j = 0; j < 8; j++) w[ii][q][j] = *(const float2*)(wrow + ks * 2 + j * 64);
    }
  }

  const int ilg = tid & 15;
  const int b4g = tid >> 4;  // for tid<64
  const float bh0 = b_hh[0 * HDIM + i0 + ilg];
  const float bh1 = b_hh[1 * HDIM + i0 + ilg];
  const float bh2 = b_hh[2 * HDIM + i0 + ilg];

  u64* slot = thw + (size_t)g * 2 * 1024;

  __shared__ float hs[2][4][512];
  __shared__ float red[192][34];
  __shared__ float gsum[208];

  float pmax = -3.0e38f;

  float cxr = 0.f, cxz = 0.f, cxn = 0.f;
  if (tid < 64) {
    const size_t xo = (size_t)(bbase + b4g) * SS * G3 + (i0 + ilg);
    cxr = toF(xi[xo]); cxz = toF(xi[xo + HDIM]); cxn = toF(xi[xo + 2 * HDIM]);
  }

  for (int s = 0; s < SS; s++) {
    // prefetch next step's xi a full step ahead
    float nxr = 0.f, nxz = 0.f, nxn = 0.f;
    if (tid < 64 && s + 1 < SS) {
      const size_t xo = ((size_t)(bbase + b4g) * SS + (s + 1)) * G3 + (i0 + ilg);
      nxr = toF(xi[xo]); nxz = toF(xi[xo + HDIM]); nxn = toF(xi[xo + 2 * HDIM]);
    }

    float* hcur = &hs[s & 1][0][0];
    if (s == 0) {
#pragma unroll
      for (int j = 0; j < 8; j++) hcur[j * 256 + tid] = 0.f;
    } else {
      const u64* src = slot + (size_t)(s & 1) * 1024 + tid;  // W = j*256+tid -> chain j, pair tid
      const u32 need = (u32)s;
      u64 v[4];
#pragma unroll
      for (int j = 0; j < 4; j++)
        v[j] = __hip_atomic_load(src + j * 256, __ATOMIC_RELAXED, __HIP_MEMORY_SCOPE_AGENT);
      u32 pend = 0;
#pragma unroll
      for (int j = 0; j < 4; j++)
        if ((u32)(v[j] & 0xFFFFu) != need) pend |= 1u << j;
      int guard = 0;
      while (pend && guard < (1 << 20)) {
        __builtin_amdgcn_s_sleep(1);
#pragma unroll
        for (int j = 0; j < 4; j++)
          if (pend & (1u << j))
            v[j] = __hip_atomic_load(src + j * 256, __ATOMIC_RELAXED, __HIP_MEMORY_SCOPE_AGENT);
#pragma unroll
        for (int j = 0; j < 4; j++)
          if ((pend & (1u << j)) && (u32)(v[j] & 0xFFFFu) == need) pend &= ~(1u << j);
        guard++;
      }
#pragma unroll
      for (int j = 0; j < 4; j++) {
        const float a = __uint_as_float((u32)(v[j] >> 40) << 8);
        const float b = __uint_as_float((u32)((v[j] >> 16) & 0xFFFFFFu) << 8);
        *(float2*)&hcur[j * 512 + 2 * tid] = make_float2(a, b);
      }
    }
    __syncthreads();  // S1: h staged

    // partial dots
#pragma unroll
    for (int b4 = 0; b4 < 4; b4++) {
      float a00 = 0.f, a01 = 0.f, a02 = 0.f, a10 = 0.f, a11 = 0.f, a12 = 0.f;
#pragma unroll
      for (int j = 0; j < 8; j++) {
        const float2 hv = *(const float2*)&hcur[b4 * 512 + ks * 2 + j * 64];
        a00 += w[0][0][j].x * hv.x + w[0][0][j].y * hv.y;
        a01 += w[0][1][j].x * hv.x + w[0][1][j].y * hv.y;
        a02 += w[0][2][j].x * hv.x + w[0][2][j].y * hv.y;
        a10 += w[1][0][j].x * hv.x + w[1][0][j].y * hv.y;
        a11 += w[1][1][j].x * hv.x + w[1][1][j].y * hv.y;
        a12 += w[1][2][j].x * hv.x + w[1][2][j].y * hv.y;
      }
      const int o0 = (i2 * 2) * 12 + b4 * 3;
      red[o0 + 0][ks] = a00; red[o0 + 1][ks] = a01; red[o0 + 2][ks] = a02;
      red[o0 + 12][ks] = a10; red[o0 + 13][ks] = a11; red[o0 + 14][ks] = a12;
    }
    __syncthreads();  // S2

    if (tid < 192) {
      float acc = 0.f;
      const float* r = &red[tid][0];
#pragma unroll
      for (int k = 0; k < 32; k += 2) {
        const float2 t2 = *(const float2*)(r + k);
        acc += t2.x + t2.y;
      }
      gsum[tid] = acc;
    }
    __syncthreads();  // S3

    if (tid < 64) {
      const int c0i = ilg * 12 + b4g * 3;
      const float hr = bh0 + gsum[c0i + 0];
      const float hz = bh1 + gsum[c0i + 1];
      const float hn = bh2 + gsum[c0i + 2];
      const float r = 1.f / (1.f + expf(-(cxr + hr)));
      const float z = 1.f / (1.f + expf(-(cxz + hz)));
      const float n = tanhf(cxn + r * hn);
      const float hp = hcur[b4g * 512 + i0 + ilg];
      const float hnew = (1.f - z) * n + z * hp;
      pmax = fmaxf(pmax, hnew);
      const float pv = __shfl_xor(hnew, 1, 64);  // pair partner (ilg^1), single wave
      if ((ilg & 1) == 0) {
        const u32 abits = ((__float_as_uint(hnew) + 0x80u) >> 8) & 0xFFFFFFu;
        const u32 bbits = ((__float_as_uint(pv) + 0x80u) >> 8) & 0xFFFFFFu;
        const u64 pkt = ((u64)abits << 40) | ((u64)bbits << 16) | (u64)(u32)(s + 1);
        const int W = b4g * 256 + (i0 >> 1) + (ilg >> 1);
        __hip_atomic_store(slot + (size_t)((s + 1) & 1) * 1024 + W, pkt,
                           __ATOMIC_RELAXED, __HIP_MEMORY_SCOPE_AGENT);
      }
    }
    cxr = nxr; cxz = nxz; cxn = nxn;
    // no 4th barrier: next step stages into hs[(s+1)&1]; red/gsum reuse is two barriers away
  }

  if (tid < 64) pooled[(size_t)(bbase + b4g) * HDIM + i0 + ilg] = pmax;
}

// ---------------- K4: out = pooled @ W_proj^T + b_proj ----------------------------------------------
__global__ void k_out(const float* __restrict__ pooled, const float* __restrict__ W_proj,
                      const float* __restrict__ b_proj, float* __restrict__ out) {
  const int t = threadIdx.x;  // 64 threads
  const int b = t >> 1, c = t & 1;
  const float* p = pooled + (size_t)b * HDIM;
  const float* wr = W_proj + (size_t)c * HDIM;
  float acc = 0.f;
#pragma unroll 4
  for (int k = 0; k < HDIM; k += 4) {
    float4 pv = *(const float4*)(p + k);
    float4 wv = *(const float4*)(wr + k);
    acc += pv.x * wv.x + pv.y * wv.y + pv.z * wv.z + pv.w * wv.w;
  }
  out[b * CC + c] = acc + b_proj[c];
}

extern "C" void kernel_launch(void* const* d_in, const int* in_sizes, int n_in,
                              void* d_out, int out_size, void* d_ws, size_t ws_size,
                              hipStream_t stream) {
  const int* x = (const int*)d_in[0];
  const float* emb = (const float*)d_in[1];
  const float* unk = (const float*)d_in[2];
  const float* induction = (const float*)d_in[3];
  const float* W_ih = (const float*)d_in[4];
  const float* W_hh = (const float*)d_in[5];
  const float* b_ih = (const float*)d_in[6];
  const float* b_hh = (const float*)d_in[7];
  const float* W_proj = (const float*)d_in[8];
  const float* b_proj = (const float*)d_in[9];
  float* out = (float*)d_out;

  const size_t xi_f32 = (size_t)BB * SS * G3 * 4;
  const size_t xi_b16 = (size_t)BB * SS * G3 * 2;
  const size_t thw_sz = (size_t)8 * 2 * 1024 * 8;  // 128 KB
  const size_t tail = thw_sz + (size_t)BB * HDIM * 4 + EDIM * 4 + 4096;
  const bool usef32 = ws_size >= xi_f32 + tail;

  char* p = (char*)d_ws;
  void* xi = p;
  p += ((usef32 ? xi_f32 : xi_b16) + 255) & ~(size_t)255;
  u64* thw = (u64*)p;         p += thw_sz;
  float* pooled = (float*)p;  p += (size_t)BB * HDIM * 4;
  float* induced = (float*)p;

  k_init<<<17, 256, 0, stream>>>(induction, unk, induced, thw);
  if (usef32) {
    k_xi<float><<<dim3(12, 128), 256, 0, stream>>>(x, emb, induced, W_ih, b_ih, (float*)xi);
    k_gru<float><<<256, 256, 0, stream>>>((const float*)xi, W_hh, b_hh, thw, pooled);
  } else {
    k_xi<__hip_bfloat16><<<dim3(12, 128), 256, 0, stream>>>(x, emb, induced, W_ih, b_ih,
                                                            (__hip_bfloat16*)xi);
    k_gru<__hip_bfloat16><<<256, 256, 0, stream>>>((const __hip_bfloat16*)xi, W_hh, b_hh, thw, pooled);
  }
  k_out<<<1, 64, 0, stream>>>(pooled, W_proj, b_proj, out);
}